// Round 7
// baseline (748.062 us; speedup 1.0000x reference)
//
#include <hip/hip_runtime.h>

#define N_ATOMS 60000
#define FPD 120
#define HD 512
#define EE 3
#define BB 600
#define NNZ_C 5000000
#define NFORCE (3 * N_ATOMS)
#define TB 64  // atoms per block: 2x weight reuse vs 32 (L2-BW-bound regime)

typedef unsigned short ushort_t;
typedef unsigned int uint_t;
typedef __attribute__((ext_vector_type(8))) __bf16 bf16x8;
typedef __attribute__((ext_vector_type(4))) float f32x4;
typedef __attribute__((ext_vector_type(4))) int i32x4;

union BF8 { f32x4 f; bf16x8 h; };

__device__ __forceinline__ ushort_t f2bf(float x) {
    uint_t u = __builtin_bit_cast(uint_t, x);
    u = (u + 0x7FFFu + ((u >> 16) & 1u)) >> 16;
    return (ushort_t)u;
}
__device__ __forceinline__ float bf2f(ushort_t s) {
    uint_t u = ((uint_t)s) << 16;
    return __builtin_bit_cast(float, u);
}
__device__ __forceinline__ float fast_tanh(float x) {
    float e2 = __expf(2.f * x);
    return fmaf(-2.f, __frcp_rn(e2 + 1.f), 1.f);
}

// ---------------- build per-element atom lists (block-aggregated atomics) -----
__global__ __launch_bounds__(256) void build_lists(const int* __restrict__ z,
                                                   int* __restrict__ counts,
                                                   int* __restrict__ lists) {
    __shared__ int lc[3];
    __shared__ int lbase[3];
    const int t = threadIdx.x;
    if (t < 3) lc[t] = 0;
    __syncthreads();
    const int i = blockIdx.x * 256 + t;
    int e = 0, pos = 0;
    if (i < N_ATOMS) {
        int zi = z[i];
        e = (zi == 1) ? 0 : ((zi == 8) ? 1 : 2);
        pos = atomicAdd(&lc[e], 1);
    }
    __syncthreads();
    if (t < 3) lbase[t] = atomicAdd(&counts[t], lc[t]);
    __syncthreads();
    if (i < N_ATOMS) lists[e * N_ATOMS + lbase[e] + pos] = i;
}

// ---------------- pack weights into MFMA B-fragment order (bf16) ----------------
// Lane L of B-frag holds B[k = ks*32 + (L>>4)*8 + j][n = ct*16 + (L&15)], j=0..7.
// ks OUTER, ct inner -> per-iteration wave loads span 8KB contiguous.
__global__ void pack_W2(const float* __restrict__ W2, ushort_t* __restrict__ W2p,
                        ushort_t* __restrict__ W2Tp) {
    int p = blockIdx.x * 256 + threadIdx.x;
    if (p >= EE * 16 * 32 * 512) return;
    int j = p & 7, L = (p >> 3) & 63, ct = (p >> 9) & 31, ks = (p >> 14) & 15, e = p >> 18;
    int k = ks * 32 + ((L >> 4) << 3) + j;
    int n = (ct << 4) + (L & 15);
    W2p[p]  = f2bf(W2[((e << 9) + k) * 512 + n]);
    W2Tp[p] = f2bf(W2[((e << 9) + n) * 512 + k]);
}
__global__ void pack_W1(const float* __restrict__ W1, ushort_t* __restrict__ W1p) {
    int p = blockIdx.x * 256 + threadIdx.x;
    if (p >= EE * 4 * 32 * 512) return;
    int j = p & 7, L = (p >> 3) & 63, ct = (p >> 9) & 31, ks = (p >> 14) & 3, e = p >> 16;
    int k = ks * 32 + ((L >> 4) << 3) + j;
    int n = (ct << 4) + (L & 15);
    W1p[p] = (k < FPD) ? f2bf(W1[(e * FPD + k) * 512 + n]) : (ushort_t)0;
}
__global__ void pack_W1T(const float* __restrict__ W1, ushort_t* __restrict__ W1Tp) {
    int p = blockIdx.x * 256 + threadIdx.x;
    if (p >= EE * 16 * 8 * 512) return;
    int j = p & 7, L = (p >> 3) & 63, ct = (p >> 9) & 7, ks = (p >> 12) & 15, e = p >> 16;
    int k = ks * 32 + ((L >> 4) << 3) + j;
    int n = (ct << 4) + (L & 15);
    W1Tp[p] = (n < FPD) ? f2bf(W1[(e * FPD + n) * 512 + k]) : (ushort_t)0;
}

#define STR 520
#define FSTR 136

// ---------------- fused fwd+bwd MLP, 64 atoms/block, MFMA ----------------
// 64 atoms/block halves weight traffic per atom (L2-BW-bound regime).
// LDS ~136KB -> 1 block/CU (4 waves); BW model says bytes beat occupancy here.
__global__ __launch_bounds__(256, 1) void mlp_mfma(
    const float* __restrict__ fps, const int* __restrict__ image_idx,
    const float* __restrict__ b1, const float* __restrict__ b2,
    const float* __restrict__ W3, const float* __restrict__ b3,
    const ushort_t* __restrict__ W1p, const ushort_t* __restrict__ W2p,
    const ushort_t* __restrict__ W2Tp, const ushort_t* __restrict__ W1Tp,
    const int* __restrict__ counts, const int* __restrict__ lists,
    float* __restrict__ energy, ushort_t* __restrict__ g) {
    __shared__ ushort_t sH1[TB * STR];  // h1, later dh1   (66.5KB)
    __shared__ ushort_t sD[TB * STR];   // fp tile, later dh2 (66.5KB)
    __shared__ float sW3[512];
    __shared__ float eAcc[TB];
    __shared__ int sAtom[TB];
    __shared__ int sImg[TB];

    const int e = blockIdx.x % EE;
    const int tile = blockIdx.x / EE;
    const int cnt = counts[e];
    const int base = tile * TB;
    if (base >= cnt) return;
    const int nA = min(TB, cnt - base);
    const int* lst = lists + e * N_ATOMS + base;

    const int t = threadIdx.x;
    const int w = t >> 6, lane = t & 63, quad = lane >> 4, lc = lane & 15;

    if (t < TB) {
        int a = (t < nA) ? lst[t] : -1;
        sAtom[t] = a;
        sImg[t] = (a >= 0) ? image_idx[a] : 0;
        eAcc[t] = 0.f;
    }
    for (int i = t; i < 512; i += 256) sW3[i] = W3[e * 512 + i];
    // fp tile (nontemporal: read-once stream; keep weights L2-resident)
    for (int i = t; i < TB * 128; i += 256) {
        int a = i >> 7, f = i & 127;
        float v = 0.f;
        if (f < FPD && a < nA) v = __builtin_nontemporal_load(&fps[(long long)lst[a] * FPD + f]);
        sD[a * FSTR + f] = f2bf(v);
    }
    __syncthreads();

    float b1c[8], b2c[8];
#pragma unroll
    for (int ct = 0; ct < 8; ct++) {
        int col = w * 128 + ct * 16 + lc;
        b1c[ct] = b1[e * 512 + col];
        b2c[ct] = b2[e * 512 + col];
    }

    f32x4 acc[4][8];

    // ---- stage 1: h1 = tanh(fp @ W1 + b1) ----
#pragma unroll
    for (int rt = 0; rt < 4; rt++)
#pragma unroll
        for (int ct = 0; ct < 8; ct++) acc[rt][ct] = (f32x4)0.f;
    {
        const ushort_t* wbase = W1p + ((size_t)(e * 4) * 32 + w * 8) * 512 + lane * 8;
#pragma unroll
        for (int ks = 0; ks < 4; ks++) {
            bf16x8 a0 = *(const bf16x8*)((const char*)sD + lc * (FSTR * 2) + ks * 64 + quad * 16);
            bf16x8 a1 = *(const bf16x8*)((const char*)sD + (16 + lc) * (FSTR * 2) + ks * 64 + quad * 16);
            bf16x8 a2 = *(const bf16x8*)((const char*)sD + (32 + lc) * (FSTR * 2) + ks * 64 + quad * 16);
            bf16x8 a3 = *(const bf16x8*)((const char*)sD + (48 + lc) * (FSTR * 2) + ks * 64 + quad * 16);
#pragma unroll
            for (int ct = 0; ct < 8; ct++) {
                BF8 b;
                b.f = *(const f32x4*)(wbase + ((size_t)ks * 32 + ct) * 512);
                acc[0][ct] = __builtin_amdgcn_mfma_f32_16x16x32_bf16(a0, b.h, acc[0][ct], 0, 0, 0);
                acc[1][ct] = __builtin_amdgcn_mfma_f32_16x16x32_bf16(a1, b.h, acc[1][ct], 0, 0, 0);
                acc[2][ct] = __builtin_amdgcn_mfma_f32_16x16x32_bf16(a2, b.h, acc[2][ct], 0, 0, 0);
                acc[3][ct] = __builtin_amdgcn_mfma_f32_16x16x32_bf16(a3, b.h, acc[3][ct], 0, 0, 0);
            }
        }
    }
#pragma unroll
    for (int ct = 0; ct < 8; ct++) {
        int col = w * 128 + ct * 16 + lc;
#pragma unroll
        for (int rt = 0; rt < 4; rt++)
#pragma unroll
            for (int r = 0; r < 4; r++) {
                int row = rt * 16 + quad * 4 + r;
                sH1[row * STR + col] = f2bf(fast_tanh(acc[rt][ct][r] + b1c[ct]));
            }
    }
    __syncthreads();

    // ---- stage 2: h2 = tanh(h1 @ W2 + b2); dh2; energy ----
#pragma unroll
    for (int rt = 0; rt < 4; rt++)
#pragma unroll
        for (int ct = 0; ct < 8; ct++) acc[rt][ct] = (f32x4)0.f;
    {
        const ushort_t* wbase = W2p + ((size_t)(e * 16) * 32 + w * 8) * 512 + lane * 8;
#pragma unroll
        for (int ks = 0; ks < 16; ks++) {
            bf16x8 a0 = *(const bf16x8*)((const char*)sH1 + lc * (STR * 2) + ks * 64 + quad * 16);
            bf16x8 a1 = *(const bf16x8*)((const char*)sH1 + (16 + lc) * (STR * 2) + ks * 64 + quad * 16);
            bf16x8 a2 = *(const bf16x8*)((const char*)sH1 + (32 + lc) * (STR * 2) + ks * 64 + quad * 16);
            bf16x8 a3 = *(const bf16x8*)((const char*)sH1 + (48 + lc) * (STR * 2) + ks * 64 + quad * 16);
#pragma unroll
            for (int ct = 0; ct < 8; ct++) {
                BF8 b;
                b.f = *(const f32x4*)(wbase + (size_t)ks * 32 * 512 + (size_t)ct * 512);
                acc[0][ct] = __builtin_amdgcn_mfma_f32_16x16x32_bf16(a0, b.h, acc[0][ct], 0, 0, 0);
                acc[1][ct] = __builtin_amdgcn_mfma_f32_16x16x32_bf16(a1, b.h, acc[1][ct], 0, 0, 0);
                acc[2][ct] = __builtin_amdgcn_mfma_f32_16x16x32_bf16(a2, b.h, acc[2][ct], 0, 0, 0);
                acc[3][ct] = __builtin_amdgcn_mfma_f32_16x16x32_bf16(a3, b.h, acc[3][ct], 0, 0, 0);
            }
        }
    }
    {
        float ep[4][4];
#pragma unroll
        for (int rt = 0; rt < 4; rt++)
#pragma unroll
            for (int r = 0; r < 4; r++) ep[rt][r] = 0.f;
#pragma unroll
        for (int ct = 0; ct < 8; ct++) {
            int col = w * 128 + ct * 16 + lc;
            float w3c = sW3[col];
#pragma unroll
            for (int rt = 0; rt < 4; rt++)
#pragma unroll
                for (int r = 0; r < 4; r++) {
                    int row = rt * 16 + quad * 4 + r;
                    float h2 = fast_tanh(acc[rt][ct][r] + b2c[ct]);
                    ep[rt][r] += h2 * w3c;
                    sD[row * STR + col] = f2bf(w3c * (1.f - h2 * h2));
                }
        }
#pragma unroll
        for (int rt = 0; rt < 4; rt++)
#pragma unroll
            for (int r = 0; r < 4; r++) {
                float p = ep[rt][r];
                p += __shfl_xor(p, 1);
                p += __shfl_xor(p, 2);
                p += __shfl_xor(p, 4);
                p += __shfl_xor(p, 8);
                if (lc == 0) atomicAdd(&eAcc[rt * 16 + quad * 4 + r], p);
            }
    }
    __syncthreads();

    if (t < nA) atomicAdd(&energy[sImg[t]], eAcc[t] + b3[e]);

    // ---- stage 5: dh1 = (dh2 @ W2^T) * (1-h1^2) ----
#pragma unroll
    for (int rt = 0; rt < 4; rt++)
#pragma unroll
        for (int ct = 0; ct < 8; ct++) acc[rt][ct] = (f32x4)0.f;
    {
        const ushort_t* wbase = W2Tp + ((size_t)(e * 16) * 32 + w * 8) * 512 + lane * 8;
#pragma unroll
        for (int ks = 0; ks < 16; ks++) {
            bf16x8 a0 = *(const bf16x8*)((const char*)sD + lc * (STR * 2) + ks * 64 + quad * 16);
            bf16x8 a1 = *(const bf16x8*)((const char*)sD + (16 + lc) * (STR * 2) + ks * 64 + quad * 16);
            bf16x8 a2 = *(const bf16x8*)((const char*)sD + (32 + lc) * (STR * 2) + ks * 64 + quad * 16);
            bf16x8 a3 = *(const bf16x8*)((const char*)sD + (48 + lc) * (STR * 2) + ks * 64 + quad * 16);
#pragma unroll
            for (int ct = 0; ct < 8; ct++) {
                BF8 b;
                b.f = *(const f32x4*)(wbase + (size_t)ks * 32 * 512 + (size_t)ct * 512);
                acc[0][ct] = __builtin_amdgcn_mfma_f32_16x16x32_bf16(a0, b.h, acc[0][ct], 0, 0, 0);
                acc[1][ct] = __builtin_amdgcn_mfma_f32_16x16x32_bf16(a1, b.h, acc[1][ct], 0, 0, 0);
                acc[2][ct] = __builtin_amdgcn_mfma_f32_16x16x32_bf16(a2, b.h, acc[2][ct], 0, 0, 0);
                acc[3][ct] = __builtin_amdgcn_mfma_f32_16x16x32_bf16(a3, b.h, acc[3][ct], 0, 0, 0);
            }
        }
    }
#pragma unroll
    for (int ct = 0; ct < 8; ct++) {
        int col = w * 128 + ct * 16 + lc;
#pragma unroll
        for (int rt = 0; rt < 4; rt++)
#pragma unroll
            for (int r = 0; r < 4; r++) {
                int row = rt * 16 + quad * 4 + r;
                float h1v = bf2f(sH1[row * STR + col]);
                acc[rt][ct][r] *= (1.f - h1v * h1v);
            }
    }
    __syncthreads();
#pragma unroll
    for (int ct = 0; ct < 8; ct++) {
        int col = w * 128 + ct * 16 + lc;
#pragma unroll
        for (int rt = 0; rt < 4; rt++)
#pragma unroll
            for (int r = 0; r < 4; r++) {
                int row = rt * 16 + quad * 4 + r;
                sH1[row * STR + col] = f2bf(acc[rt][ct][r]);  // sH1 = dh1
            }
    }
    __syncthreads();

    // ---- stage 7: g = dh1 @ W1^T ----
    f32x4 acc7[4][2];
#pragma unroll
    for (int rt = 0; rt < 4; rt++)
#pragma unroll
        for (int c = 0; c < 2; c++) acc7[rt][c] = (f32x4)0.f;
    {
        const ushort_t* wbase = W1Tp + ((size_t)(e * 16) * 8 + w * 2) * 512 + lane * 8;
#pragma unroll
        for (int ks = 0; ks < 16; ks++) {
            bf16x8 a0 = *(const bf16x8*)((const char*)sH1 + lc * (STR * 2) + ks * 64 + quad * 16);
            bf16x8 a1 = *(const bf16x8*)((const char*)sH1 + (16 + lc) * (STR * 2) + ks * 64 + quad * 16);
            bf16x8 a2 = *(const bf16x8*)((const char*)sH1 + (32 + lc) * (STR * 2) + ks * 64 + quad * 16);
            bf16x8 a3 = *(const bf16x8*)((const char*)sH1 + (48 + lc) * (STR * 2) + ks * 64 + quad * 16);
#pragma unroll
            for (int c = 0; c < 2; c++) {
                BF8 b;
                b.f = *(const f32x4*)(wbase + (size_t)ks * 8 * 512 + (size_t)c * 512);
                acc7[0][c] = __builtin_amdgcn_mfma_f32_16x16x32_bf16(a0, b.h, acc7[0][c], 0, 0, 0);
                acc7[1][c] = __builtin_amdgcn_mfma_f32_16x16x32_bf16(a1, b.h, acc7[1][c], 0, 0, 0);
                acc7[2][c] = __builtin_amdgcn_mfma_f32_16x16x32_bf16(a2, b.h, acc7[2][c], 0, 0, 0);
                acc7[3][c] = __builtin_amdgcn_mfma_f32_16x16x32_bf16(a3, b.h, acc7[3][c], 0, 0, 0);
            }
        }
    }
#pragma unroll
    for (int c = 0; c < 2; c++) {
        int col = (w * 2 + c) * 16 + lc;
#pragma unroll
        for (int rt = 0; rt < 4; rt++)
#pragma unroll
            for (int r = 0; r < 4; r++) {
                int row = rt * 16 + quad * 4 + r;
                if (col < FPD && row < nA)
                    g[(long long)sAtom[row] * FPD + col] = f2bf(acc7[rt][c][r]);
            }
    }
}

// ---------------- sparse force scatter, privatized, 4 nnz/thread ---------
// NOTE: __builtin_nontemporal_load needs clang ext_vector types, NOT HIP's
// int4/float4 classes (compile error on gfx950).
__global__ __launch_bounds__(256) void scatter_forces(
    const int* __restrict__ rows, const int* __restrict__ cols,
    const float* __restrict__ vals, const ushort_t* __restrict__ g,
    float* __restrict__ forcesP) {
    int k = blockIdx.x * 256 + threadIdx.x;
    if (k >= NNZ_C / 4) return;
    int slot = blockIdx.x & 7;
    i32x4 r = __builtin_nontemporal_load((const i32x4*)rows + k);
    i32x4 c = __builtin_nontemporal_load((const i32x4*)cols + k);
    f32x4 v = __builtin_nontemporal_load((const f32x4*)vals + k);
    float* fp = forcesP + (size_t)slot * NFORCE;
    atomicAdd(&fp[c.x], -v.x * bf2f(g[r.x]));
    atomicAdd(&fp[c.y], -v.y * bf2f(g[r.y]));
    atomicAdd(&fp[c.z], -v.z * bf2f(g[r.z]));
    atomicAdd(&fp[c.w], -v.w * bf2f(g[r.w]));
}

__global__ void reduce_forces(const float* __restrict__ forcesP, float* __restrict__ forces) {
    int i = blockIdx.x * blockDim.x + threadIdx.x;
    if (i >= NFORCE) return;
    float s = 0.f;
#pragma unroll
    for (int x = 0; x < 8; x++) s += forcesP[x * NFORCE + i];
    forces[i] = s;
}

extern "C" void kernel_launch(void* const* d_in, const int* in_sizes, int n_in,
                              void* d_out, int out_size, void* d_ws, size_t ws_size,
                              hipStream_t stream) {
    const float* fps = (const float*)d_in[0];
    const int* z = (const int*)d_in[1];
    const int* img = (const int*)d_in[2];
    const float* W1 = (const float*)d_in[3];
    const float* b1 = (const float*)d_in[4];
    const float* W2 = (const float*)d_in[5];
    const float* b2 = (const float*)d_in[6];
    const float* W3 = (const float*)d_in[7];
    const float* b3 = (const float*)d_in[8];
    const int* rows = (const int*)d_in[9];
    const int* cols = (const int*)d_in[10];
    const float* vals = (const float*)d_in[11];

    float* out = (float*)d_out;
    float* energy = out;
    float* forces = out + BB;

    char* ws = (char*)d_ws;
    int* counts = (int*)ws;                           // 256 B
    int* lists = (int*)(ws + 256);                    // 720000 B
    ushort_t* W1p = (ushort_t*)(ws + 720384);         // 393216 B
    ushort_t* W2p = (ushort_t*)(ws + 1113600);        // 1572864 B
    ushort_t* W2Tp = (ushort_t*)(ws + 2686464);       // 1572864 B
    ushort_t* W1Tp = (ushort_t*)(ws + 4259328);       // 393216 B
    ushort_t* g = (ushort_t*)(ws + 4652544);          // 14400000 B
    float* forcesP = (float*)(ws + 19052544);         // 5760000 B
    (void)in_sizes; (void)n_in; (void)out_size; (void)ws_size;

    (void)hipMemsetAsync(d_out, 0, (size_t)(BB + NFORCE) * sizeof(float), stream);
    (void)hipMemsetAsync(counts, 0, 256, stream);
    (void)hipMemsetAsync(forcesP, 0, (size_t)8 * NFORCE * sizeof(float), stream);

    build_lists<<<(N_ATOMS + 255) / 256, 256, 0, stream>>>(z, counts, lists);
    pack_W2<<<(EE * 16 * 32 * 512 + 255) / 256, 256, 0, stream>>>(W2, W2p, W2Tp);
    pack_W1<<<(EE * 4 * 32 * 512 + 255) / 256, 256, 0, stream>>>(W1, W1p);
    pack_W1T<<<(EE * 16 * 8 * 512 + 255) / 256, 256, 0, stream>>>(W1, W1Tp);

    int tiles = (N_ATOMS + TB - 1) / TB;
    mlp_mfma<<<EE * tiles, 256, 0, stream>>>(fps, img, b1, b2, W3, b3,
                                             W1p, W2p, W2Tp, W1Tp,
                                             counts, lists, energy, g);
    scatter_forces<<<(NNZ_C / 4 + 255) / 256, 256, 0, stream>>>(rows, cols, vals, g, forcesP);
    reduce_forces<<<(NFORCE + 255) / 256, 256, 0, stream>>>(forcesP, forces);
}

// Round 8
// 578.625 us; speedup vs baseline: 1.2928x; 1.2928x over previous
//
#include <hip/hip_runtime.h>

#define N_ATOMS 60000
#define FPD 120
#define HD 512
#define EE 3
#define BB 600
#define NNZ_C 5000000
#define NFORCE (3 * N_ATOMS)
#define TB 32   // atoms per block
#define NW 8    // waves per block (512 threads): 16 waves/CU at 2 blocks/CU

typedef unsigned short ushort_t;
typedef unsigned int uint_t;
typedef __attribute__((ext_vector_type(8))) __bf16 bf16x8;
typedef __attribute__((ext_vector_type(4))) float f32x4;
typedef __attribute__((ext_vector_type(4))) int i32x4;

union BF8 { f32x4 f; bf16x8 h; };

__device__ __forceinline__ ushort_t f2bf(float x) {
    uint_t u = __builtin_bit_cast(uint_t, x);
    u = (u + 0x7FFFu + ((u >> 16) & 1u)) >> 16;
    return (ushort_t)u;
}
__device__ __forceinline__ float bf2f(ushort_t s) {
    uint_t u = ((uint_t)s) << 16;
    return __builtin_bit_cast(float, u);
}
__device__ __forceinline__ float fast_tanh(float x) {
    float e2 = __expf(2.f * x);
    return fmaf(-2.f, __frcp_rn(e2 + 1.f), 1.f);
}

// ---------------- build per-element atom lists (block-aggregated atomics) -----
__global__ __launch_bounds__(256) void build_lists(const int* __restrict__ z,
                                                   int* __restrict__ counts,
                                                   int* __restrict__ lists) {
    __shared__ int lc[3];
    __shared__ int lbase[3];
    const int t = threadIdx.x;
    if (t < 3) lc[t] = 0;
    __syncthreads();
    const int i = blockIdx.x * 256 + t;
    int e = 0, pos = 0;
    if (i < N_ATOMS) {
        int zi = z[i];
        e = (zi == 1) ? 0 : ((zi == 8) ? 1 : 2);
        pos = atomicAdd(&lc[e], 1);
    }
    __syncthreads();
    if (t < 3) lbase[t] = atomicAdd(&counts[t], lc[t]);
    __syncthreads();
    if (i < N_ATOMS) lists[e * N_ATOMS + lbase[e] + pos] = i;
}

// ---------------- pack weights into MFMA B-fragment order (bf16) ----------------
// Lane L of B-frag holds B[k = ks*32 + (L>>4)*8 + j][n = ct*16 + (L&15)], j=0..7.
// ks OUTER, ct inner -> per-iteration block loads span contiguous KBs (all L2
// channels).
__global__ void pack_W2(const float* __restrict__ W2, ushort_t* __restrict__ W2p,
                        ushort_t* __restrict__ W2Tp) {
    int p = blockIdx.x * 256 + threadIdx.x;
    if (p >= EE * 16 * 32 * 512) return;
    int j = p & 7, L = (p >> 3) & 63, ct = (p >> 9) & 31, ks = (p >> 14) & 15, e = p >> 18;
    int k = ks * 32 + ((L >> 4) << 3) + j;
    int n = (ct << 4) + (L & 15);
    W2p[p]  = f2bf(W2[((e << 9) + k) * 512 + n]);
    W2Tp[p] = f2bf(W2[((e << 9) + n) * 512 + k]);
}
__global__ void pack_W1(const float* __restrict__ W1, ushort_t* __restrict__ W1p) {
    int p = blockIdx.x * 256 + threadIdx.x;
    if (p >= EE * 4 * 32 * 512) return;
    int j = p & 7, L = (p >> 3) & 63, ct = (p >> 9) & 31, ks = (p >> 14) & 3, e = p >> 16;
    int k = ks * 32 + ((L >> 4) << 3) + j;
    int n = (ct << 4) + (L & 15);
    W1p[p] = (k < FPD) ? f2bf(W1[(e * FPD + k) * 512 + n]) : (ushort_t)0;
}
__global__ void pack_W1T(const float* __restrict__ W1, ushort_t* __restrict__ W1Tp) {
    int p = blockIdx.x * 256 + threadIdx.x;
    if (p >= EE * 16 * 8 * 512) return;
    int j = p & 7, L = (p >> 3) & 63, ct = (p >> 9) & 7, ks = (p >> 12) & 15, e = p >> 16;
    int k = ks * 32 + ((L >> 4) << 3) + j;
    int n = (ct << 4) + (L & 15);
    W1Tp[p] = (n < FPD) ? f2bf(W1[(e * FPD + n) * 512 + k]) : (ushort_t)0;
}

#define STR 520
#define FSTR 136

// ---------------- fused fwd+bwd MLP, 32 atoms/block, 8 waves, MFMA ----------------
// 512 threads: each wave covers 64 cols (4 ct). LDS ~69KB -> 2 blocks/CU =
// 16 waves/CU (4/SIMD): 2x the in-flight weight loads of the 256-thread
// version at the same traffic. Latency-bound regime => waves win.
__global__ __launch_bounds__(512, 4) void mlp_mfma(
    const float* __restrict__ fps, const int* __restrict__ image_idx,
    const float* __restrict__ b1, const float* __restrict__ b2,
    const float* __restrict__ W3, const float* __restrict__ b3,
    const ushort_t* __restrict__ W1p, const ushort_t* __restrict__ W2p,
    const ushort_t* __restrict__ W2Tp, const ushort_t* __restrict__ W1Tp,
    const int* __restrict__ counts, const int* __restrict__ lists,
    float* __restrict__ energy, ushort_t* __restrict__ g) {
    __shared__ ushort_t sH1[TB * STR];  // h1, later dh1   (33.3KB)
    __shared__ ushort_t sD[TB * STR];   // fp tile, later dh2 (33.3KB)
    __shared__ float sW3[512];
    __shared__ float eAcc[TB];
    __shared__ int sAtom[TB];
    __shared__ int sImg[TB];

    const int e = blockIdx.x % EE;
    const int tile = blockIdx.x / EE;
    const int cnt = counts[e];
    const int base = tile * TB;
    if (base >= cnt) return;
    const int nA = min(TB, cnt - base);
    const int* lst = lists + e * N_ATOMS + base;

    const int t = threadIdx.x;
    const int w = t >> 6, lane = t & 63, quad = lane >> 4, lc = lane & 15;

    if (t < TB) {
        int a = (t < nA) ? lst[t] : -1;
        sAtom[t] = a;
        sImg[t] = (a >= 0) ? image_idx[a] : 0;
        eAcc[t] = 0.f;
    }
    for (int i = t; i < 512; i += 512) sW3[i] = W3[e * 512 + i];
    for (int i = t; i < TB * 128; i += 512) {
        int a = i >> 7, f = i & 127;
        float v = 0.f;
        if (f < FPD && a < nA) v = __builtin_nontemporal_load(&fps[(long long)lst[a] * FPD + f]);
        sD[a * FSTR + f] = f2bf(v);
    }
    __syncthreads();

    float b1c[4], b2c[4];
#pragma unroll
    for (int c = 0; c < 4; c++) {
        int col = w * 64 + c * 16 + lc;
        b1c[c] = b1[e * 512 + col];
        b2c[c] = b2[e * 512 + col];
    }

    f32x4 acc[2][4];

    // ---- stage 1: h1 = tanh(fp @ W1 + b1) ----
#pragma unroll
    for (int rt = 0; rt < 2; rt++)
#pragma unroll
        for (int c = 0; c < 4; c++) acc[rt][c] = (f32x4)0.f;
    {
        const ushort_t* wbase = W1p + ((size_t)(e * 4) * 32 + w * 4) * 512 + lane * 8;
#pragma unroll
        for (int ks = 0; ks < 4; ks++) {
            bf16x8 a0 = *(const bf16x8*)((const char*)sD + lc * (FSTR * 2) + ks * 64 + quad * 16);
            bf16x8 a1 = *(const bf16x8*)((const char*)sD + (16 + lc) * (FSTR * 2) + ks * 64 + quad * 16);
#pragma unroll
            for (int c = 0; c < 4; c++) {
                BF8 b;
                b.f = *(const f32x4*)(wbase + ((size_t)ks * 32 + c) * 512);
                acc[0][c] = __builtin_amdgcn_mfma_f32_16x16x32_bf16(a0, b.h, acc[0][c], 0, 0, 0);
                acc[1][c] = __builtin_amdgcn_mfma_f32_16x16x32_bf16(a1, b.h, acc[1][c], 0, 0, 0);
            }
        }
    }
#pragma unroll
    for (int c = 0; c < 4; c++) {
        int col = w * 64 + c * 16 + lc;
#pragma unroll
        for (int rt = 0; rt < 2; rt++)
#pragma unroll
            for (int r = 0; r < 4; r++) {
                int row = rt * 16 + quad * 4 + r;
                sH1[row * STR + col] = f2bf(fast_tanh(acc[rt][c][r] + b1c[c]));
            }
    }
    __syncthreads();

    // ---- stage 2: h2 = tanh(h1 @ W2 + b2); dh2; energy ----
#pragma unroll
    for (int rt = 0; rt < 2; rt++)
#pragma unroll
        for (int c = 0; c < 4; c++) acc[rt][c] = (f32x4)0.f;
    {
        const ushort_t* wbase = W2p + ((size_t)(e * 16) * 32 + w * 4) * 512 + lane * 8;
#pragma unroll 2
        for (int ks = 0; ks < 16; ks++) {
            bf16x8 a0 = *(const bf16x8*)((const char*)sH1 + lc * (STR * 2) + ks * 64 + quad * 16);
            bf16x8 a1 = *(const bf16x8*)((const char*)sH1 + (16 + lc) * (STR * 2) + ks * 64 + quad * 16);
#pragma unroll
            for (int c = 0; c < 4; c++) {
                BF8 b;
                b.f = *(const f32x4*)(wbase + (size_t)ks * 32 * 512 + (size_t)c * 512);
                acc[0][c] = __builtin_amdgcn_mfma_f32_16x16x32_bf16(a0, b.h, acc[0][c], 0, 0, 0);
                acc[1][c] = __builtin_amdgcn_mfma_f32_16x16x32_bf16(a1, b.h, acc[1][c], 0, 0, 0);
            }
        }
    }
    {
        float ep[2][4];
#pragma unroll
        for (int rt = 0; rt < 2; rt++)
#pragma unroll
            for (int r = 0; r < 4; r++) ep[rt][r] = 0.f;
#pragma unroll
        for (int c = 0; c < 4; c++) {
            int col = w * 64 + c * 16 + lc;
            float w3c = sW3[col];
#pragma unroll
            for (int rt = 0; rt < 2; rt++)
#pragma unroll
                for (int r = 0; r < 4; r++) {
                    int row = rt * 16 + quad * 4 + r;
                    float h2 = fast_tanh(acc[rt][c][r] + b2c[c]);
                    ep[rt][r] += h2 * w3c;
                    sD[row * STR + col] = f2bf(w3c * (1.f - h2 * h2));
                }
        }
#pragma unroll
        for (int rt = 0; rt < 2; rt++)
#pragma unroll
            for (int r = 0; r < 4; r++) {
                float p = ep[rt][r];
                p += __shfl_xor(p, 1);
                p += __shfl_xor(p, 2);
                p += __shfl_xor(p, 4);
                p += __shfl_xor(p, 8);
                if (lc == 0) atomicAdd(&eAcc[rt * 16 + quad * 4 + r], p);
            }
    }
    __syncthreads();

    if (t < nA) atomicAdd(&energy[sImg[t]], eAcc[t] + b3[e]);

    // ---- stage 5: dh1 = (dh2 @ W2^T) * (1-h1^2) ----
#pragma unroll
    for (int rt = 0; rt < 2; rt++)
#pragma unroll
        for (int c = 0; c < 4; c++) acc[rt][c] = (f32x4)0.f;
    {
        const ushort_t* wbase = W2Tp + ((size_t)(e * 16) * 32 + w * 4) * 512 + lane * 8;
#pragma unroll 2
        for (int ks = 0; ks < 16; ks++) {
            bf16x8 a0 = *(const bf16x8*)((const char*)sD + lc * (STR * 2) + ks * 64 + quad * 16);
            bf16x8 a1 = *(const bf16x8*)((const char*)sD + (16 + lc) * (STR * 2) + ks * 64 + quad * 16);
#pragma unroll
            for (int c = 0; c < 4; c++) {
                BF8 b;
                b.f = *(const f32x4*)(wbase + (size_t)ks * 32 * 512 + (size_t)c * 512);
                acc[0][c] = __builtin_amdgcn_mfma_f32_16x16x32_bf16(a0, b.h, acc[0][c], 0, 0, 0);
                acc[1][c] = __builtin_amdgcn_mfma_f32_16x16x32_bf16(a1, b.h, acc[1][c], 0, 0, 0);
            }
        }
    }
#pragma unroll
    for (int c = 0; c < 4; c++) {
        int col = w * 64 + c * 16 + lc;
#pragma unroll
        for (int rt = 0; rt < 2; rt++)
#pragma unroll
            for (int r = 0; r < 4; r++) {
                int row = rt * 16 + quad * 4 + r;
                float h1v = bf2f(sH1[row * STR + col]);
                acc[rt][c][r] *= (1.f - h1v * h1v);
            }
    }
    __syncthreads();
#pragma unroll
    for (int c = 0; c < 4; c++) {
        int col = w * 64 + c * 16 + lc;
#pragma unroll
        for (int rt = 0; rt < 2; rt++)
#pragma unroll
            for (int r = 0; r < 4; r++) {
                int row = rt * 16 + quad * 4 + r;
                sH1[row * STR + col] = f2bf(acc[rt][c][r]);  // sH1 = dh1
            }
    }
    __syncthreads();

    // ---- stage 7: g = dh1 @ W1^T (128 cols = 8 ct; 1 ct per wave) ----
    f32x4 acc7[2];
#pragma unroll
    for (int rt = 0; rt < 2; rt++) acc7[rt] = (f32x4)0.f;
    {
        const ushort_t* wbase = W1Tp + ((size_t)(e * 16) * 8 + w) * 512 + lane * 8;
#pragma unroll 2
        for (int ks = 0; ks < 16; ks++) {
            bf16x8 a0 = *(const bf16x8*)((const char*)sH1 + lc * (STR * 2) + ks * 64 + quad * 16);
            bf16x8 a1 = *(const bf16x8*)((const char*)sH1 + (16 + lc) * (STR * 2) + ks * 64 + quad * 16);
            BF8 b;
            b.f = *(const f32x4*)(wbase + (size_t)ks * 8 * 512);
            acc7[0] = __builtin_amdgcn_mfma_f32_16x16x32_bf16(a0, b.h, acc7[0], 0, 0, 0);
            acc7[1] = __builtin_amdgcn_mfma_f32_16x16x32_bf16(a1, b.h, acc7[1], 0, 0, 0);
        }
    }
    {
        int col = w * 16 + lc;
#pragma unroll
        for (int rt = 0; rt < 2; rt++)
#pragma unroll
            for (int r = 0; r < 4; r++) {
                int row = rt * 16 + quad * 4 + r;
                if (col < FPD && row < nA)
                    g[(long long)sAtom[row] * FPD + col] = f2bf(acc7[rt][r]);
            }
    }
}

// ---------------- sparse force scatter, privatized, 4 nnz/thread ---------
__global__ __launch_bounds__(256) void scatter_forces(
    const int* __restrict__ rows, const int* __restrict__ cols,
    const float* __restrict__ vals, const ushort_t* __restrict__ g,
    float* __restrict__ forcesP) {
    int k = blockIdx.x * 256 + threadIdx.x;
    if (k >= NNZ_C / 4) return;
    int slot = blockIdx.x & 7;
    i32x4 r = __builtin_nontemporal_load((const i32x4*)rows + k);
    i32x4 c = __builtin_nontemporal_load((const i32x4*)cols + k);
    f32x4 v = __builtin_nontemporal_load((const f32x4*)vals + k);
    float* fp = forcesP + (size_t)slot * NFORCE;
    atomicAdd(&fp[c.x], -v.x * bf2f(g[r.x]));
    atomicAdd(&fp[c.y], -v.y * bf2f(g[r.y]));
    atomicAdd(&fp[c.z], -v.z * bf2f(g[r.z]));
    atomicAdd(&fp[c.w], -v.w * bf2f(g[r.w]));
}

__global__ void reduce_forces(const float* __restrict__ forcesP, float* __restrict__ forces) {
    int i = blockIdx.x * blockDim.x + threadIdx.x;
    if (i >= NFORCE) return;
    float s = 0.f;
#pragma unroll
    for (int x = 0; x < 8; x++) s += forcesP[x * NFORCE + i];
    forces[i] = s;
}

extern "C" void kernel_launch(void* const* d_in, const int* in_sizes, int n_in,
                              void* d_out, int out_size, void* d_ws, size_t ws_size,
                              hipStream_t stream) {
    const float* fps = (const float*)d_in[0];
    const int* z = (const int*)d_in[1];
    const int* img = (const int*)d_in[2];
    const float* W1 = (const float*)d_in[3];
    const float* b1 = (const float*)d_in[4];
    const float* W2 = (const float*)d_in[5];
    const float* b2 = (const float*)d_in[6];
    const float* W3 = (const float*)d_in[7];
    const float* b3 = (const float*)d_in[8];
    const int* rows = (const int*)d_in[9];
    const int* cols = (const int*)d_in[10];
    const float* vals = (const float*)d_in[11];

    float* out = (float*)d_out;
    float* energy = out;
    float* forces = out + BB;

    char* ws = (char*)d_ws;
    int* counts = (int*)ws;                           // 256 B
    int* lists = (int*)(ws + 256);                    // 720000 B
    ushort_t* W1p = (ushort_t*)(ws + 720384);         // 393216 B
    ushort_t* W2p = (ushort_t*)(ws + 1113600);        // 1572864 B
    ushort_t* W2Tp = (ushort_t*)(ws + 2686464);       // 1572864 B
    ushort_t* W1Tp = (ushort_t*)(ws + 4259328);       // 393216 B
    ushort_t* g = (ushort_t*)(ws + 4652544);          // 14400000 B
    float* forcesP = (float*)(ws + 19052544);         // 5760000 B
    (void)in_sizes; (void)n_in; (void)out_size; (void)ws_size;

    (void)hipMemsetAsync(d_out, 0, (size_t)(BB + NFORCE) * sizeof(float), stream);
    (void)hipMemsetAsync(counts, 0, 256, stream);
    (void)hipMemsetAsync(forcesP, 0, (size_t)8 * NFORCE * sizeof(float), stream);

    build_lists<<<(N_ATOMS + 255) / 256, 256, 0, stream>>>(z, counts, lists);
    pack_W2<<<(EE * 16 * 32 * 512 + 255) / 256, 256, 0, stream>>>(W2, W2p, W2Tp);
    pack_W1<<<(EE * 4 * 32 * 512 + 255) / 256, 256, 0, stream>>>(W1, W1p);
    pack_W1T<<<(EE * 16 * 8 * 512 + 255) / 256, 256, 0, stream>>>(W1, W1Tp);

    int tiles = (N_ATOMS + TB - 1) / TB;
    mlp_mfma<<<EE * tiles, 512, 0, stream>>>(fps, img, b1, b2, W3, b3,
                                             W1p, W2p, W2Tp, W1Tp,
                                             counts, lists, energy, g);
    scatter_forces<<<(NNZ_C / 4 + 255) / 256, 256, 0, stream>>>(rows, cols, vals, g, forcesP);
    reduce_forces<<<(NFORCE + 255) / 256, 256, 0, stream>>>(forcesP, forces);
}